// Round 1
// baseline (740.538 us; speedup 1.0000x reference)
//
#include <hip/hip_runtime.h>
#include <math.h>

// Problem dims
#define BB 512
#define DE 1024
#define DM 1024
#define NA 512
#define NP 256

static __device__ __forceinline__ float4 ld4(const float* p) {
    return *reinterpret_cast<const float4*>(p);
}

// ---------------- block reduction helpers (256 threads = 4 waves) -------------
__device__ __forceinline__ float blkred_sum(float v, volatile float* sm) {
    for (int off = 32; off; off >>= 1) v += __shfl_xor(v, off);
    int lane = threadIdx.x & 63, w = threadIdx.x >> 6;
    __syncthreads();
    if (lane == 0) sm[w] = v;
    __syncthreads();
    return (sm[0] + sm[1]) + (sm[2] + sm[3]);
}
__device__ __forceinline__ float blkred_max(float v, volatile float* sm) {
    for (int off = 32; off; off >>= 1) v = fmaxf(v, __shfl_xor(v, off));
    int lane = threadIdx.x & 63, w = threadIdx.x >> 6;
    __syncthreads();
    if (lane == 0) sm[w] = v;
    __syncthreads();
    return fmaxf(fmaxf(sm[0], sm[1]), fmaxf(sm[2], sm[3]));
}

// ---------------- sinusoidal positional encoding table (257 x 512) ------------
__global__ __launch_bounds__(256) void pe_kernel(float* __restrict__ pe) {
    int p = blockIdx.x;      // 0..256
    int i = threadIdx.x;     // 0..255 (pair index)
    const float c = -0.017988946039015984f; // -ln(10000)/512
    float div = expf((float)(2 * i) * c);
    float arg = (float)p * div;
    pe[p * NA + 2 * i]     = sinf(arg);
    pe[p * NA + 2 * i + 1] = cosf(arg);
}

// ---------------- generic 64x64 tiled fp32 GEMM -------------------------------
// C[M,N] = A[M,K] @ (TB ? B[N,K]^T : B[K,N]) (+bias)(+relu)
// Assumes M % 64 == 0, K % 16 == 0. N guarded (for N=257).
template<int TB, int BIAS, int RELU>
__global__ __launch_bounds__(256) void gemm64(const float* __restrict__ A,
                                              const float* __restrict__ Bm,
                                              const float* __restrict__ bias,
                                              float* __restrict__ C,
                                              int M, int N, int K) {
    __shared__ float As[16][68];
    __shared__ float Bs[16][68];
    const int tid = threadIdx.x;
    const int tx = tid & 15, ty = tid >> 4;
    const int tx2 = tx * 2, ty2 = ty * 2;
    const int row0 = blockIdx.y * 64, col0 = blockIdx.x * 64;

    // staging indices
    const int la_r = tid >> 2;        // 0..63
    const int la_k = (tid & 3) * 4;   // 0,4,8,12
    const int lb_r = tid >> 4;        // 0..15
    const int lb_c = (tid & 15) * 4;  // 0..60

    float acc[4][4] = {};

    for (int k0 = 0; k0 < K; k0 += 16) {
        float4 av = ld4(A + (size_t)(row0 + la_r) * K + k0 + la_k);
        As[la_k + 0][la_r] = av.x; As[la_k + 1][la_r] = av.y;
        As[la_k + 2][la_r] = av.z; As[la_k + 3][la_r] = av.w;
        if (TB) {
            int n = col0 + la_r;
            float4 bv = make_float4(0.f, 0.f, 0.f, 0.f);
            if (n < N) bv = ld4(Bm + (size_t)n * K + k0 + la_k);
            Bs[la_k + 0][la_r] = bv.x; Bs[la_k + 1][la_r] = bv.y;
            Bs[la_k + 2][la_r] = bv.z; Bs[la_k + 3][la_r] = bv.w;
        } else {
            // N is a multiple of 64 in all NN uses here -> no guard needed
            float4 bv = ld4(Bm + (size_t)(k0 + lb_r) * N + col0 + lb_c);
            *reinterpret_cast<float4*>(&Bs[lb_r][lb_c]) = bv;
        }
        __syncthreads();
        #pragma unroll
        for (int kk = 0; kk < 16; ++kk) {
            float a[4], b[4];
            a[0] = As[kk][ty2];      a[1] = As[kk][ty2 + 1];
            a[2] = As[kk][ty2 + 32]; a[3] = As[kk][ty2 + 33];
            b[0] = Bs[kk][tx2];      b[1] = Bs[kk][tx2 + 1];
            b[2] = Bs[kk][tx2 + 32]; b[3] = Bs[kk][tx2 + 33];
            #pragma unroll
            for (int i = 0; i < 4; ++i)
                #pragma unroll
                for (int j = 0; j < 4; ++j)
                    acc[i][j] = fmaf(a[i], b[j], acc[i][j]);
        }
        __syncthreads();
    }

    #pragma unroll
    for (int i = 0; i < 4; ++i) {
        int r = row0 + ty2 + (i & 1) + 32 * (i >> 1);
        float* crow = C + (size_t)r * N;
        #pragma unroll
        for (int j = 0; j < 4; ++j) {
            int c = col0 + tx2 + (j & 1) + 32 * (j >> 1);
            if (c < N) {
                float val = acc[i][j];
                if (BIAS) val += bias[c];
                if (RELU) val = fmaxf(val, 0.f);
                crow[c] = val;
            }
        }
    }
}

// ---------------- pass 1 over phi: both score dot-products --------------------
// grid: BB*4 blocks, 256 threads (4 waves). Each wave: 16 rows of one b.
__global__ __launch_bounds__(256) void phi_dot(const float* __restrict__ phi,
                                               const float* __restrict__ u_out,
                                               const float* __restrict__ u_in,
                                               float* __restrict__ sdo,
                                               float* __restrict__ sdi) {
    int b = blockIdx.x >> 2;
    int q = blockIdx.x & 3;
    int wave = threadIdx.x >> 6, lane = threadIdx.x & 63;
    float4 uo0 = ld4(u_out + (size_t)b * NA + lane * 4);
    float4 uo1 = ld4(u_out + (size_t)b * NA + 256 + lane * 4);
    float4 ui0 = ld4(u_in + (size_t)b * NA + lane * 4);
    float4 ui1 = ld4(u_in + (size_t)b * NA + 256 + lane * 4);
    for (int r = 0; r < 16; ++r) {
        int n = q * 64 + wave * 16 + r;
        const float* row = phi + ((size_t)b * NP + n) * NA;
        float4 x0 = ld4(row + lane * 4);
        float4 x1 = ld4(row + 256 + lane * 4);
        float d0 = uo0.x * x0.x + uo0.y * x0.y + uo0.z * x0.z + uo0.w * x0.w
                 + uo1.x * x1.x + uo1.y * x1.y + uo1.z * x1.z + uo1.w * x1.w;
        float d1 = ui0.x * x0.x + ui0.y * x0.y + ui0.z * x0.z + ui0.w * x0.w
                 + ui1.x * x1.x + ui1.y * x1.y + ui1.z * x1.z + ui1.w * x1.w;
        for (int off = 32; off; off >>= 1) {
            d0 += __shfl_xor(d0, off);
            d1 += __shfl_xor(d1, off);
        }
        if (lane == 0) {
            sdo[b * NP + n] = d0;
            sdi[b * NP + n] = d1;
        }
    }
}

// ---------------- softmax prep --------------------------------------------
// out-attn: full softmax -> normalized weights aw.
// in-attn rows 1..256: unnormalized e = exp(s - m1); store m1, sumE.
__global__ __launch_bounds__(256) void attn_prep(const float* __restrict__ sdo,
                                                 const float* __restrict__ sdi,
                                                 const float* __restrict__ po,
                                                 const float* __restrict__ pi,
                                                 float* __restrict__ aw,
                                                 float* __restrict__ ew,
                                                 float* __restrict__ m1s,
                                                 float* __restrict__ sumEs) {
    __shared__ float sm[4];
    int b = blockIdx.x, t = threadIdx.x;
    const float inv = 0.03125f; // 1/sqrt(1024)
    float so = (sdo[b * NP + t] + po[b * NP + t]) * inv;
    float si = (sdi[b * NP + t] + pi[b * 257 + t + 1]) * inv;

    float mo = blkred_max(so, sm);
    float eo = expf(so - mo);
    float Zo = blkred_sum(eo, sm);
    aw[b * NP + t] = eo / Zo;

    float m1 = blkred_max(si, sm);
    float e = expf(si - m1);
    float Z1 = blkred_sum(e, sm);
    ew[b * NP + t] = e;
    if (t == 0) { m1s[b] = m1; sumEs[b] = Z1; }
}

// ---------------- pass 2 over phi: both weighted sums (row-split x4) ----------
__global__ __launch_bounds__(256) void phi_wsum(const float* __restrict__ phi,
                                                const float* __restrict__ aw,
                                                const float* __restrict__ ew,
                                                float* __restrict__ vp,
                                                float* __restrict__ Sp) {
    int blk = blockIdx.x, b = blk >> 2, s = blk & 3;
    int t = threadIdx.x;
    __shared__ float a_l[64], e_l[64];
    if (t < 64) {
        a_l[t] = aw[b * NP + s * 64 + t];
        e_l[t] = ew[b * NP + s * 64 + t];
    }
    __syncthreads();
    float2 va = {0.f, 0.f}, Sa = {0.f, 0.f};
    const float* base = phi + ((size_t)b * NP + s * 64) * NA + t * 2;
    #pragma unroll 4
    for (int n = 0; n < 64; ++n) {
        float2 x = *reinterpret_cast<const float2*>(base + (size_t)n * NA);
        va.x = fmaf(a_l[n], x.x, va.x);
        va.y = fmaf(a_l[n], x.y, va.y);
        Sa.x = fmaf(e_l[n], x.x, Sa.x);
        Sa.y = fmaf(e_l[n], x.y, Sa.y);
    }
    *reinterpret_cast<float2*>(&vp[((size_t)b * 4 + s) * NA + t * 2]) = va;
    *reinterpret_cast<float2*>(&Sp[((size_t)b * 4 + s) * NA + t * 2]) = Sa;
}

// ---------------- combine partials + row-0 fixup -> v, w ----------------------
__global__ __launch_bounds__(256) void fixup(const float* __restrict__ vp,
                                             const float* __restrict__ Sp,
                                             const float* __restrict__ u_in,
                                             const float* __restrict__ pi,
                                             const float* __restrict__ m1s,
                                             const float* __restrict__ sumEs,
                                             float* __restrict__ v,
                                             float* __restrict__ w) {
    __shared__ float sm[4];
    int b = blockIdx.x, t = threadIdx.x;
    float2 v2 = {0.f, 0.f}, S2 = {0.f, 0.f};
    #pragma unroll
    for (int s = 0; s < 4; ++s) {
        float2 a = *reinterpret_cast<const float2*>(&vp[((size_t)b * 4 + s) * NA + t * 2]);
        float2 c = *reinterpret_cast<const float2*>(&Sp[((size_t)b * 4 + s) * NA + t * 2]);
        v2.x += a.x; v2.y += a.y;
        S2.x += c.x; S2.y += c.y;
    }
    *reinterpret_cast<float2*>(&v[(size_t)b * NA + t * 2]) = v2;
    float2 u2 = *reinterpret_cast<const float2*>(&u_in[(size_t)b * NA + t * 2]);
    float part = u2.x * v2.x + u2.y * v2.y;
    float dot = blkred_sum(part, sm);
    float s0 = (dot + pi[b * 257]) * 0.03125f;
    float e0 = expf(s0 - m1s[b]);
    float Z = sumEs[b] + e0;
    float invZ = 1.0f / Z;
    float2 w2;
    w2.x = (e0 * v2.x + S2.x) * invZ;
    w2.y = (e0 * v2.y + S2.y) * invZ;
    *reinterpret_cast<float2*>(&w[(size_t)b * NA + t * 2]) = w2;
}

// ---------------- concat x = [h_s, ctx] --------------------------------------
__global__ __launch_bounds__(256) void concat_x(const float* __restrict__ h_s,
                                                const float* __restrict__ ctx,
                                                float* __restrict__ x) {
    int i = blockIdx.x * 256 + threadIdx.x;   // over BB*2048
    int b = i >> 11, c = i & 2047;
    x[i] = (c < DE) ? h_s[(size_t)b * DE + c] : ctx[(size_t)b * DM + (c - DE)];
}

// ---------------- final: out = softmax(v + logits) ---------------------------
__global__ __launch_bounds__(256) void final_softmax(const float* __restrict__ v,
                                                     float* __restrict__ out) {
    __shared__ float sm[4];
    int b = blockIdx.x, t = threadIdx.x;
    float z0 = out[(size_t)b * NA + t] + v[(size_t)b * NA + t];
    float z1 = out[(size_t)b * NA + 256 + t] + v[(size_t)b * NA + 256 + t];
    float m = blkred_max(fmaxf(z0, z1), sm);
    float e0 = expf(z0 - m), e1 = expf(z1 - m);
    float Z = blkred_sum(e0 + e1, sm);
    out[(size_t)b * NA + t] = e0 / Z;
    out[(size_t)b * NA + 256 + t] = e1 / Z;
}

// ---------------- launch ------------------------------------------------------
extern "C" void kernel_launch(void* const* d_in, const int* in_sizes, int n_in,
                              void* d_out, int out_size, void* d_ws, size_t ws_size,
                              hipStream_t stream) {
    const float* h_s = (const float*)d_in[0];
    const float* phi = (const float*)d_in[1];
    const float* WQo = (const float*)d_in[2];
    const float* WKo = (const float*)d_in[3];
    const float* WQi = (const float*)d_in[4];
    const float* WKi = (const float*)d_in[5];
    const float* WVi = (const float*)d_in[6];
    const float* W1  = (const float*)d_in[7];
    const float* b1  = (const float*)d_in[8];
    const float* W2  = (const float*)d_in[9];
    const float* b2  = (const float*)d_in[10];
    float* out = (float*)d_out;
    float* ws  = (float*)d_ws;

    // workspace layout (floats)
    size_t off = 0;
    float* pe    = ws + off; off += 257 * NA;        // 131584
    float* qout  = ws + off; off += (size_t)BB * DM; // also start of x
    float* qin   = ws + off; off += (size_t)BB * DM;
    float* uout  = ws + off; off += (size_t)BB * NA; // also start of hidden
    float* uin   = ws + off; off += (size_t)BB * NA;
    float* po    = ws + off; off += (size_t)BB * NP;
    float* pi    = ws + off; off += (size_t)BB * 257;
    float* sdo   = ws + off; off += (size_t)BB * NP;
    float* sdi   = ws + off; off += (size_t)BB * NP;
    float* aw    = ws + off; off += (size_t)BB * NP;
    float* ew    = ws + off; off += (size_t)BB * NP;
    float* m1s   = ws + off; off += BB;
    float* sumEs = ws + off; off += BB;
    float* vp    = ws + off; off += (size_t)BB * 4 * NA;
    float* Sp    = ws + off; off += (size_t)BB * 4 * NA;
    float* v     = ws + off; off += (size_t)BB * NA;
    float* w     = ws + off; off += (size_t)BB * NA;
    float* ctx   = ws + off; off += (size_t)BB * DM;
    float* x      = qout;  // alias: q_out/q_in dead after u GEMMs
    float* hidden = uout;  // alias: u_out/u_in dead after fixup

    pe_kernel<<<257, 256, 0, stream>>>(pe);

    // q = h_s @ WQ (NN)
    gemm64<0,0,0><<<dim3(16, 8), 256, 0, stream>>>(h_s, WQo, nullptr, qout, BB, DM, DE);
    gemm64<0,0,0><<<dim3(16, 8), 256, 0, stream>>>(h_s, WQi, nullptr, qin,  BB, DM, DE);
    // u = q @ WK^T (NT)
    gemm64<1,0,0><<<dim3(8, 8), 256, 0, stream>>>(qout, WKo, nullptr, uout, BB, NA, DM);
    gemm64<1,0,0><<<dim3(8, 8), 256, 0, stream>>>(qin,  WKi, nullptr, uin,  BB, NA, DM);
    // pe dots: po = u_out @ pe[0:256]^T ; pi = u_in @ pe[0:257]^T (NT)
    gemm64<1,0,0><<<dim3(4, 8), 256, 0, stream>>>(uout, pe, nullptr, po, BB, NP, NA);
    gemm64<1,0,0><<<dim3(5, 8), 256, 0, stream>>>(uin,  pe, nullptr, pi, BB, 257, NA);

    // pass 1 over phi: score dots for both heads
    phi_dot<<<BB * 4, 256, 0, stream>>>(phi, uout, uin, sdo, sdi);
    attn_prep<<<BB, 256, 0, stream>>>(sdo, sdi, po, pi, aw, ew, m1s, sumEs);
    // pass 2 over phi: both weighted sums
    phi_wsum<<<BB * 4, 256, 0, stream>>>(phi, aw, ew, vp, Sp);
    fixup<<<BB, 256, 0, stream>>>(vp, Sp, uin, pi, m1s, sumEs, v, w);

    // ctx = w @ WV_in (NN)
    gemm64<0,0,0><<<dim3(16, 8), 256, 0, stream>>>(w, WVi, nullptr, ctx, BB, DM, NA);
    // x = [h_s, ctx]
    concat_x<<<BB * 2048 / 256, 256, 0, stream>>>(h_s, ctx, x);
    // hidden = relu(x @ W1 + b1)
    gemm64<0,1,1><<<dim3(16, 8), 256, 0, stream>>>(x, W1, b1, hidden, BB, DM, DE + DM);
    // logits = hidden @ W2 + b2 -> d_out
    gemm64<0,1,0><<<dim3(8, 8), 256, 0, stream>>>(hidden, W2, b2, out, BB, NA, DM);
    // out = softmax(v + logits)
    final_softmax<<<BB, 256, 0, stream>>>(v, out);
}

// Round 2
// 344.499 us; speedup vs baseline: 2.1496x; 2.1496x over previous
//
#include <hip/hip_runtime.h>
#include <math.h>

// Problem dims
#define BB 512
#define DE 1024
#define DM 1024
#define NA 512
#define NP 256

typedef unsigned short ushort_t;
typedef __attribute__((ext_vector_type(8))) short s8v;   // 8 bf16 (4 VGPRs)
typedef __attribute__((ext_vector_type(4))) float f4v;   // 4 fp32 acc

static __device__ __forceinline__ float4 ld4(const float* p) {
    return *reinterpret_cast<const float4*>(p);
}

// RNE float -> bf16 bits
__device__ __forceinline__ unsigned bf16h(float x) {
    unsigned u = __float_as_uint(x);
    return (u + 0x7FFFu + ((u >> 16) & 1u)) >> 16;
}
__device__ __forceinline__ float bf16f(unsigned h) { return __uint_as_float(h << 16); }

__device__ __forceinline__ f4v mfma16(s8v a, s8v b, f4v c) {
    return __builtin_amdgcn_mfma_f32_16x16x32_bf16(a, b, c, 0, 0, 0);
}

// ---------------- block reduction helpers (256 threads = 4 waves) -------------
__device__ __forceinline__ float blkred_sum(float v, volatile float* sm) {
    for (int off = 32; off; off >>= 1) v += __shfl_xor(v, off);
    int lane = threadIdx.x & 63, w = threadIdx.x >> 6;
    __syncthreads();
    if (lane == 0) sm[w] = v;
    __syncthreads();
    return (sm[0] + sm[1]) + (sm[2] + sm[3]);
}
__device__ __forceinline__ float blkred_max(float v, volatile float* sm) {
    for (int off = 32; off; off >>= 1) v = fmaxf(v, __shfl_xor(v, off));
    int lane = threadIdx.x & 63, w = threadIdx.x >> 6;
    __syncthreads();
    if (lane == 0) sm[w] = v;
    __syncthreads();
    return fmaxf(fmaxf(sm[0], sm[1]), fmaxf(sm[2], sm[3]));
}

// ---------------- sinusoidal PE table -> bf16 hi/lo (257 x 512) ---------------
__global__ __launch_bounds__(256) void pe_kernel(ushort_t* __restrict__ ph,
                                                 ushort_t* __restrict__ pl) {
    int p = blockIdx.x;      // 0..256
    int i = threadIdx.x;     // pair index
    const float c = -0.017988946039015984f; // -ln(10000)/512
    float div = expf((float)(2 * i) * c);
    float arg = (float)p * div;
    float s = sinf(arg), co = cosf(arg);
    unsigned hs = bf16h(s), hc = bf16h(co);
    unsigned ls = bf16h(s - bf16f(hs)), lc = bf16h(co - bf16f(hc));
    *reinterpret_cast<unsigned*>(ph + p * NA + 2 * i) = hs | (hc << 16);
    *reinterpret_cast<unsigned*>(pl + p * NA + 2 * i) = ls | (lc << 16);
}

// ---------------- weight prep: elementwise fp32 -> bf16 hi/lo -----------------
__global__ __launch_bounds__(256) void conv_ew(const float* __restrict__ W,
                                               ushort_t* __restrict__ Hh,
                                               ushort_t* __restrict__ Hl, int n) {
    int i = (blockIdx.x * 256 + threadIdx.x) * 4;
    if (i >= n) return;
    float4 f = ld4(W + i);
    float ff[4] = {f.x, f.y, f.z, f.w};
    unsigned h[4], l[4];
    #pragma unroll
    for (int q = 0; q < 4; ++q) { h[q] = bf16h(ff[q]); l[q] = bf16h(ff[q] - bf16f(h[q])); }
    *reinterpret_cast<uint2*>(Hh + i) = make_uint2(h[0] | (h[1] << 16), h[2] | (h[3] << 16));
    *reinterpret_cast<uint2*>(Hl + i) = make_uint2(l[0] | (l[1] << 16), l[2] | (l[3] << 16));
}

// ---------------- weight prep: transpose [K][N] -> [N][K] + hi/lo -------------
__global__ __launch_bounds__(256) void conv_tr(const float* __restrict__ W,
                                               ushort_t* __restrict__ Th,
                                               ushort_t* __restrict__ Tl,
                                               int K, int N) {
    __shared__ float t[32][33];
    int k0 = blockIdx.y * 32, n0 = blockIdx.x * 32;
    int ty = threadIdx.x >> 3, tx = (threadIdx.x & 7) * 4;
    float4 f = ld4(W + (size_t)(k0 + ty) * N + n0 + tx);
    t[ty][tx] = f.x; t[ty][tx + 1] = f.y; t[ty][tx + 2] = f.z; t[ty][tx + 3] = f.w;
    __syncthreads();
    unsigned h[4], l[4];
    #pragma unroll
    for (int q = 0; q < 4; ++q) {
        float x = t[tx + q][ty];
        h[q] = bf16h(x); l[q] = bf16h(x - bf16f(h[q]));
    }
    size_t o = (size_t)(n0 + ty) * K + k0 + tx;
    *reinterpret_cast<uint2*>(Th + o) = make_uint2(h[0] | (h[1] << 16), h[2] | (h[3] << 16));
    *reinterpret_cast<uint2*>(Tl + o) = make_uint2(l[0] | (l[1] << 16), l[2] | (l[3] << 16));
}

// ---------------- split-bf16 MFMA GEMM ----------------------------------------
// C[M,N] = A[M,K](fp32) @ Bt[N,K](bf16 hi/lo, pre-converted) (+bias)(+relu)
// 64x64 tile, BK=64, 4 waves x (2x2) 16x16x32 frags, 3 MFMA per frag (split).
// LDS XOR-swizzle: element k ^ ((row&7)<<3) keeps ds_read_b128 at bank floor.
template<int GUARD, int BIAS, int RELU>
__global__ __launch_bounds__(256) void gemm_mfma(const float* __restrict__ A,
                                                 const ushort_t* __restrict__ Bh,
                                                 const ushort_t* __restrict__ Bl,
                                                 const float* __restrict__ bias,
                                                 float* __restrict__ C,
                                                 int M, int N, int K) {
    __shared__ ushort_t sAh[4096], sAl[4096], sBh[4096], sBl[4096];
    const int tid = threadIdx.x;
    const int row0 = blockIdx.y * 64, col0 = blockIdx.x * 64;

    // staging: thread -> (row sr, k-chunk of 16)
    const int sr = tid >> 2;
    const int skb = (tid & 3) * 16;
    const int swz = (sr & 7) << 3;
    const int sidx0 = sr * 64 + (skb ^ swz);
    const int sidx1 = sr * 64 + ((skb + 8) ^ swz);

    const int wid = tid >> 6, lane = tid & 63;
    const int wm = wid & 1, wn = wid >> 1;
    const int lm = lane & 15, lk = lane >> 4;

    const int ra = wm * 32 + lm;           // A frag row (i=0); +16 for i=1
    const int rb = wn * 32 + lm;           // B frag row (j=0); +16 for j=1
    const int aswz = (ra & 7) << 3;        // (ra+16)&7 == ra&7
    const int bswz = (rb & 7) << 3;

    const float* ap = A + (size_t)(row0 + sr) * K + skb;
    const int nb = col0 + sr;
    const bool bval = !GUARD || (nb < N);
    const ushort_t* bhp = Bh + (size_t)nb * K + skb;
    const ushort_t* blp = Bl + (size_t)nb * K + skb;

    f4v acc[2][2] = {};

    for (int k0 = 0; k0 < K; k0 += 64) {
        // ---- stage A (fp32 -> hi/lo bf16) ----
        float ff[16];
        #pragma unroll
        for (int q = 0; q < 4; ++q) {
            float4 f = ld4(ap + k0 + q * 4);
            ff[q * 4 + 0] = f.x; ff[q * 4 + 1] = f.y;
            ff[q * 4 + 2] = f.z; ff[q * 4 + 3] = f.w;
        }
        unsigned hh[16], ll[16];
        #pragma unroll
        for (int q = 0; q < 16; ++q) {
            hh[q] = bf16h(ff[q]);
            ll[q] = bf16h(ff[q] - bf16f(hh[q]));
        }
        *reinterpret_cast<int4*>(&sAh[sidx0]) = make_int4(
            (int)(hh[0] | (hh[1] << 16)), (int)(hh[2] | (hh[3] << 16)),
            (int)(hh[4] | (hh[5] << 16)), (int)(hh[6] | (hh[7] << 16)));
        *reinterpret_cast<int4*>(&sAh[sidx1]) = make_int4(
            (int)(hh[8] | (hh[9] << 16)), (int)(hh[10] | (hh[11] << 16)),
            (int)(hh[12] | (hh[13] << 16)), (int)(hh[14] | (hh[15] << 16)));
        *reinterpret_cast<int4*>(&sAl[sidx0]) = make_int4(
            (int)(ll[0] | (ll[1] << 16)), (int)(ll[2] | (ll[3] << 16)),
            (int)(ll[4] | (ll[5] << 16)), (int)(ll[6] | (ll[7] << 16)));
        *reinterpret_cast<int4*>(&sAl[sidx1]) = make_int4(
            (int)(ll[8] | (ll[9] << 16)), (int)(ll[10] | (ll[11] << 16)),
            (int)(ll[12] | (ll[13] << 16)), (int)(ll[14] | (ll[15] << 16)));

        // ---- stage B (pre-converted bf16 hi/lo, [N][K]) ----
        int4 b0 = {0,0,0,0}, b1 = {0,0,0,0}, b2 = {0,0,0,0}, b3 = {0,0,0,0};
        if (bval) {
            b0 = *reinterpret_cast<const int4*>(bhp + k0);
            b1 = *reinterpret_cast<const int4*>(bhp + k0 + 8);
            b2 = *reinterpret_cast<const int4*>(blp + k0);
            b3 = *reinterpret_cast<const int4*>(blp + k0 + 8);
        }
        *reinterpret_cast<int4*>(&sBh[sidx0]) = b0;
        *reinterpret_cast<int4*>(&sBh[sidx1]) = b1;
        *reinterpret_cast<int4*>(&sBl[sidx0]) = b2;
        *reinterpret_cast<int4*>(&sBl[sidx1]) = b3;
        __syncthreads();

        // ---- 2 K-steps of 32 ----
        #pragma unroll
        for (int ks = 0; ks < 2; ++ks) {
            const int ka = (ks * 32 + lk * 8) ^ aswz;
            const int kb = (ks * 32 + lk * 8) ^ bswz;
            s8v a0h = *reinterpret_cast<const s8v*>(&sAh[ra * 64 + ka]);
            s8v a1h = *reinterpret_cast<const s8v*>(&sAh[(ra + 16) * 64 + ka]);
            s8v a0l = *reinterpret_cast<const s8v*>(&sAl[ra * 64 + ka]);
            s8v a1l = *reinterpret_cast<const s8v*>(&sAl[(ra + 16) * 64 + ka]);
            s8v b0h = *reinterpret_cast<const s8v*>(&sBh[rb * 64 + kb]);
            s8v b1h = *reinterpret_cast<const s8v*>(&sBh[(rb + 16) * 64 + kb]);
            s8v b0l = *reinterpret_cast<const s8v*>(&sBl[rb * 64 + kb]);
            s8v b1l = *reinterpret_cast<const s8v*>(&sBl[(rb + 16) * 64 + kb]);

            acc[0][0] = mfma16(a0h, b0h, acc[0][0]);
            acc[0][1] = mfma16(a0h, b1h, acc[0][1]);
            acc[1][0] = mfma16(a1h, b0h, acc[1][0]);
            acc[1][1] = mfma16(a1h, b1h, acc[1][1]);
            acc[0][0] = mfma16(a0h, b0l, acc[0][0]);
            acc[0][1] = mfma16(a0h, b1l, acc[0][1]);
            acc[1][0] = mfma16(a1h, b0l, acc[1][0]);
            acc[1][1] = mfma16(a1h, b1l, acc[1][1]);
            acc[0][0] = mfma16(a0l, b0h, acc[0][0]);
            acc[0][1] = mfma16(a0l, b1h, acc[0][1]);
            acc[1][0] = mfma16(a1l, b0h, acc[1][0]);
            acc[1][1] = mfma16(a1l, b1h, acc[1][1]);
        }
        __syncthreads();
    }

    // ---- epilogue: C/D layout col=lane&15, row=(lane>>4)*4+reg ----
    #pragma unroll
    for (int i = 0; i < 2; ++i) {
        #pragma unroll
        for (int j = 0; j < 2; ++j) {
            int gc = col0 + wn * 32 + j * 16 + lm;
            if (GUARD && gc >= N) continue;
            float bv = BIAS ? bias[gc] : 0.0f;
            #pragma unroll
            for (int r = 0; r < 4; ++r) {
                int gr = row0 + wm * 32 + i * 16 + lk * 4 + r;
                float val = acc[i][j][r] + bv;
                if (RELU) val = fmaxf(val, 0.0f);
                C[(size_t)gr * N + gc] = val;
            }
        }
    }
}

// ---------------- pass 1 over phi: both score dot-products --------------------
__global__ __launch_bounds__(256) void phi_dot(const float* __restrict__ phi,
                                               const float* __restrict__ u_out,
                                               const float* __restrict__ u_in,
                                               float* __restrict__ sdo,
                                               float* __restrict__ sdi) {
    int b = blockIdx.x >> 2;
    int q = blockIdx.x & 3;
    int wave = threadIdx.x >> 6, lane = threadIdx.x & 63;
    float4 uo0 = ld4(u_out + (size_t)b * NA + lane * 4);
    float4 uo1 = ld4(u_out + (size_t)b * NA + 256 + lane * 4);
    float4 ui0 = ld4(u_in + (size_t)b * NA + lane * 4);
    float4 ui1 = ld4(u_in + (size_t)b * NA + 256 + lane * 4);
    for (int r = 0; r < 16; ++r) {
        int n = q * 64 + wave * 16 + r;
        const float* row = phi + ((size_t)b * NP + n) * NA;
        float4 x0 = ld4(row + lane * 4);
        float4 x1 = ld4(row + 256 + lane * 4);
        float d0 = uo0.x * x0.x + uo0.y * x0.y + uo0.z * x0.z + uo0.w * x0.w
                 + uo1.x * x1.x + uo1.y * x1.y + uo1.z * x1.z + uo1.w * x1.w;
        float d1 = ui0.x * x0.x + ui0.y * x0.y + ui0.z * x0.z + ui0.w * x0.w
                 + ui1.x * x1.x + ui1.y * x1.y + ui1.z * x1.z + ui1.w * x1.w;
        for (int off = 32; off; off >>= 1) {
            d0 += __shfl_xor(d0, off);
            d1 += __shfl_xor(d1, off);
        }
        if (lane == 0) {
            sdo[b * NP + n] = d0;
            sdi[b * NP + n] = d1;
        }
    }
}

// ---------------- softmax prep ------------------------------------------------
__global__ __launch_bounds__(256) void attn_prep(const float* __restrict__ sdo,
                                                 const float* __restrict__ sdi,
                                                 const float* __restrict__ po,
                                                 const float* __restrict__ pi,
                                                 float* __restrict__ aw,
                                                 float* __restrict__ ew,
                                                 float* __restrict__ m1s,
                                                 float* __restrict__ sumEs) {
    __shared__ float sm[4];
    int b = blockIdx.x, t = threadIdx.x;
    const float inv = 0.03125f; // 1/sqrt(1024)
    float so = (sdo[b * NP + t] + po[b * NP + t]) * inv;
    float si = (sdi[b * NP + t] + pi[b * 257 + t + 1]) * inv;

    float mo = blkred_max(so, sm);
    float eo = expf(so - mo);
    float Zo = blkred_sum(eo, sm);
    aw[b * NP + t] = eo / Zo;

    float m1 = blkred_max(si, sm);
    float e = expf(si - m1);
    float Z1 = blkred_sum(e, sm);
    ew[b * NP + t] = e;
    if (t == 0) { m1s[b] = m1; sumEs[b] = Z1; }
}

// ---------------- pass 2 over phi: both weighted sums -------------------------
__global__ __launch_bounds__(256) void phi_wsum(const float* __restrict__ phi,
                                                const float* __restrict__ aw,
                                                const float* __restrict__ ew,
                                                float* __restrict__ vp,
                                                float* __restrict__ Sp) {
    int blk = blockIdx.x, b = blk >> 2, s = blk & 3;
    int t = threadIdx.x;
    __shared__ float a_l[64], e_l[64];
    if (t < 64) {
        a_l[t] = aw[b * NP + s * 64 + t];
        e_l[t] = ew[b * NP + s * 64 + t];
    }
    __syncthreads();
    float2 va = {0.f, 0.f}, Sa = {0.f, 0.f};
    const float* base = phi + ((size_t)b * NP + s * 64) * NA + t * 2;
    #pragma unroll 4
    for (int n = 0; n < 64; ++n) {
        float2 x = *reinterpret_cast<const float2*>(base + (size_t)n * NA);
        va.x = fmaf(a_l[n], x.x, va.x);
        va.y = fmaf(a_l[n], x.y, va.y);
        Sa.x = fmaf(e_l[n], x.x, Sa.x);
        Sa.y = fmaf(e_l[n], x.y, Sa.y);
    }
    *reinterpret_cast<float2*>(&vp[((size_t)b * 4 + s) * NA + t * 2]) = va;
    *reinterpret_cast<float2*>(&Sp[((size_t)b * 4 + s) * NA + t * 2]) = Sa;
}

// ---------------- combine partials + row-0 fixup -> v, w ----------------------
__global__ __launch_bounds__(256) void fixup(const float* __restrict__ vp,
                                             const float* __restrict__ Sp,
                                             const float* __restrict__ u_in,
                                             const float* __restrict__ pi,
                                             const float* __restrict__ m1s,
                                             const float* __restrict__ sumEs,
                                             float* __restrict__ v,
                                             float* __restrict__ w) {
    __shared__ float sm[4];
    int b = blockIdx.x, t = threadIdx.x;
    float2 v2 = {0.f, 0.f}, S2 = {0.f, 0.f};
    #pragma unroll
    for (int s = 0; s < 4; ++s) {
        float2 a = *reinterpret_cast<const float2*>(&vp[((size_t)b * 4 + s) * NA + t * 2]);
        float2 c = *reinterpret_cast<const float2*>(&Sp[((size_t)b * 4 + s) * NA + t * 2]);
        v2.x += a.x; v2.y += a.y;
        S2.x += c.x; S2.y += c.y;
    }
    *reinterpret_cast<float2*>(&v[(size_t)b * NA + t * 2]) = v2;
    float2 u2 = *reinterpret_cast<const float2*>(&u_in[(size_t)b * NA + t * 2]);
    float part = u2.x * v2.x + u2.y * v2.y;
    float dot = blkred_sum(part, sm);
    float s0 = (dot + pi[b * 257]) * 0.03125f;
    float e0 = expf(s0 - m1s[b]);
    float Z = sumEs[b] + e0;
    float invZ = 1.0f / Z;
    float2 w2;
    w2.x = (e0 * v2.x + S2.x) * invZ;
    w2.y = (e0 * v2.y + S2.y) * invZ;
    *reinterpret_cast<float2*>(&w[(size_t)b * NA + t * 2]) = w2;
}

// ---------------- concat x = [h_s, ctx] ---------------------------------------
__global__ __launch_bounds__(256) void concat_x(const float* __restrict__ h_s,
                                                const float* __restrict__ ctx,
                                                float* __restrict__ x) {
    int i = blockIdx.x * 256 + threadIdx.x;
    int b = i >> 11, c = i & 2047;
    x[i] = (c < DE) ? h_s[(size_t)b * DE + c] : ctx[(size_t)b * DM + (c - DE)];
}

// ---------------- final: out = softmax(v + logits) ----------------------------
__global__ __launch_bounds__(256) void final_softmax(const float* __restrict__ v,
                                                     float* __restrict__ out) {
    __shared__ float sm[4];
    int b = blockIdx.x, t = threadIdx.x;
    float z0 = out[(size_t)b * NA + t] + v[(size_t)b * NA + t];
    float z1 = out[(size_t)b * NA + 256 + t] + v[(size_t)b * NA + 256 + t];
    float m = blkred_max(fmaxf(z0, z1), sm);
    float e0 = expf(z0 - m), e1 = expf(z1 - m);
    float Z = blkred_sum(e0 + e1, sm);
    out[(size_t)b * NA + t] = e0 / Z;
    out[(size_t)b * NA + 256 + t] = e1 / Z;
}

// ---------------- launch ------------------------------------------------------
extern "C" void kernel_launch(void* const* d_in, const int* in_sizes, int n_in,
                              void* d_out, int out_size, void* d_ws, size_t ws_size,
                              hipStream_t stream) {
    const float* h_s = (const float*)d_in[0];
    const float* phi = (const float*)d_in[1];
    const float* WQo = (const float*)d_in[2];
    const float* WKo = (const float*)d_in[3];
    const float* WQi = (const float*)d_in[4];
    const float* WKi = (const float*)d_in[5];
    const float* WVi = (const float*)d_in[6];
    const float* W1  = (const float*)d_in[7];
    const float* b1  = (const float*)d_in[8];
    const float* W2  = (const float*)d_in[9];
    const float* b2  = (const float*)d_in[10];
    float* out = (float*)d_out;
    float* wsf = (float*)d_ws;

    size_t off = 0;
    auto af = [&](size_t n) { float* p = wsf + off; off += (n + 3) & ~(size_t)3; return p; };
    auto au = [&](size_t n) { ushort_t* p = (ushort_t*)(wsf + off); off += ((n / 2) + 3) & ~(size_t)3; return p; };

    // bf16 hi/lo weight buffers ([N][K] layout for GEMM B-operand)
    ushort_t* peh   = au(257 * NA);      ushort_t* pel   = au(257 * NA);
    ushort_t* WQoth = au(DM * DE);       ushort_t* WQotl = au(DM * DE);
    ushort_t* WQith = au(DM * DE);       ushort_t* WQitl = au(DM * DE);
    ushort_t* WKoh  = au(DM * NA);       ushort_t* WKol  = au(DM * NA);
    ushort_t* WKih  = au(DM * NA);       ushort_t* WKil  = au(DM * NA);
    ushort_t* WVith = au(DM * NA);       ushort_t* WVitl = au(DM * NA);
    ushort_t* W1th  = au(DM * (DE+DM));  ushort_t* W1tl  = au(DM * (DE+DM));
    ushort_t* W2th  = au(NA * DM);       ushort_t* W2tl  = au(NA * DM);

    // fp32 activations
    float* qout = af((size_t)BB * DM);   // }-- contiguous: alias x = qout [BB][2048]
    float* qin  = af((size_t)BB * DM);   // }
    float* uout = af((size_t)BB * NA);   // }-- contiguous: alias hidden = uout [BB][1024]
    float* uin  = af((size_t)BB * NA);   // }
    float* po   = af((size_t)BB * NP);
    float* pi   = af((size_t)BB * 257);
    float* sdo  = af((size_t)BB * NP);
    float* sdi  = af((size_t)BB * NP);
    float* aw   = af((size_t)BB * NP);
    float* ew   = af((size_t)BB * NP);
    float* m1s  = af(BB);
    float* sumEs= af(BB);
    float* vp   = af((size_t)BB * 4 * NA);
    float* Sp   = af((size_t)BB * 4 * NA);
    float* v    = af((size_t)BB * NA);
    float* w    = af((size_t)BB * NA);
    float* ctx  = af((size_t)BB * DM);
    float* x      = qout;
    float* hidden = uout;

    // ---- weight prep (runs every launch; ~44 MB traffic) ----
    pe_kernel<<<257, 256, 0, stream>>>(peh, pel);
    conv_tr<<<dim3(DM/32, DE/32), 256, 0, stream>>>(WQo, WQoth, WQotl, DE, DM);
    conv_tr<<<dim3(DM/32, DE/32), 256, 0, stream>>>(WQi, WQith, WQitl, DE, DM);
    conv_ew<<<(NA * DM) / 1024, 256, 0, stream>>>(WKo, WKoh, WKol, NA * DM);
    conv_ew<<<(NA * DM) / 1024, 256, 0, stream>>>(WKi, WKih, WKil, NA * DM);
    conv_tr<<<dim3(DM/32, NA/32), 256, 0, stream>>>(WVi, WVith, WVitl, NA, DM);
    conv_tr<<<dim3(DM/32, (DE+DM)/32), 256, 0, stream>>>(W1, W1th, W1tl, DE + DM, DM);
    conv_tr<<<dim3(NA/32, DM/32), 256, 0, stream>>>(W2, W2th, W2tl, DM, NA);

    // ---- GEMMs (split-bf16 MFMA) ----
    gemm_mfma<0,0,0><<<dim3(16, 8), 256, 0, stream>>>(h_s, WQoth, WQotl, nullptr, qout, BB, DM, DE);
    gemm_mfma<0,0,0><<<dim3(16, 8), 256, 0, stream>>>(h_s, WQith, WQitl, nullptr, qin,  BB, DM, DE);
    gemm_mfma<0,0,0><<<dim3(8, 8),  256, 0, stream>>>(qout, WKoh, WKol, nullptr, uout, BB, NA, DM);
    gemm_mfma<0,0,0><<<dim3(8, 8),  256, 0, stream>>>(qin,  WKih, WKil, nullptr, uin,  BB, NA, DM);
    gemm_mfma<0,0,0><<<dim3(4, 8),  256, 0, stream>>>(uout, peh, pel, nullptr, po, BB, NP, NA);
    gemm_mfma<1,0,0><<<dim3(5, 8),  256, 0, stream>>>(uin,  peh, pel, nullptr, pi, BB, 257, NA);

    // ---- attention over phi (unchanged this round) ----
    phi_dot<<<BB * 4, 256, 0, stream>>>(phi, uout, uin, sdo, sdi);
    attn_prep<<<BB, 256, 0, stream>>>(sdo, sdi, po, pi, aw, ew, m1s, sumEs);
    phi_wsum<<<BB * 4, 256, 0, stream>>>(phi, aw, ew, vp, Sp);
    fixup<<<BB, 256, 0, stream>>>(vp, Sp, uin, pi, m1s, sumEs, v, w);

    // ---- tail: ctx GEMM, MLP, final softmax ----
    gemm_mfma<0,0,0><<<dim3(16, 8), 256, 0, stream>>>(w, WVith, WVitl, nullptr, ctx, BB, DM, NA);
    concat_x<<<BB * 2048 / 256, 256, 0, stream>>>(h_s, ctx, x);
    gemm_mfma<0,1,1><<<dim3(16, 8), 256, 0, stream>>>(x, W1th, W1tl, b1, hidden, BB, DM, DE + DM);
    gemm_mfma<0,1,0><<<dim3(8, 8),  256, 0, stream>>>(hidden, W2th, W2tl, b2, out, BB, NA, DM);
    final_softmax<<<BB, 256, 0, stream>>>(v, out);
}

// Round 3
// 219.739 us; speedup vs baseline: 3.3701x; 1.5678x over previous
//
#include <hip/hip_runtime.h>
#include <math.h>

// Problem dims
#define BB 512
#define DE 1024
#define DM 1024
#define NA 512
#define NP 256

typedef unsigned short ushort_t;
typedef __attribute__((ext_vector_type(8))) short s8v;   // 8 bf16 (4 VGPRs)
typedef __attribute__((ext_vector_type(4))) float f4v;   // 4 fp32 acc

static __device__ __forceinline__ float4 ld4(const float* p) {
    return *reinterpret_cast<const float4*>(p);
}

// RNE float -> bf16 bits
__device__ __forceinline__ unsigned bf16h(float x) {
    unsigned u = __float_as_uint(x);
    return (u + 0x7FFFu + ((u >> 16) & 1u)) >> 16;
}
__device__ __forceinline__ float bf16f(unsigned h) { return __uint_as_float(h << 16); }

__device__ __forceinline__ f4v mfma16(s8v a, s8v b, f4v c) {
    return __builtin_amdgcn_mfma_f32_16x16x32_bf16(a, b, c, 0, 0, 0);
}

// ---------------- block reduction helper (256 threads = 4 waves) --------------
__device__ __forceinline__ float blkred_sum(float v, volatile float* sm) {
    for (int off = 32; off; off >>= 1) v += __shfl_xor(v, off);
    int lane = threadIdx.x & 63, w = threadIdx.x >> 6;
    __syncthreads();
    if (lane == 0) sm[w] = v;
    __syncthreads();
    return (sm[0] + sm[1]) + (sm[2] + sm[3]);
}

// ================= PREP: PE table + all weight/h_s hi-lo splits ===============
__device__ __forceinline__ void d_ew(const float* __restrict__ W,
                                     ushort_t* __restrict__ Hh,
                                     ushort_t* __restrict__ Hl, int bid) {
    int i = (bid * 256 + threadIdx.x) * 4;
    float4 f = ld4(W + i);
    float ff[4] = {f.x, f.y, f.z, f.w};
    unsigned h[4], l[4];
    #pragma unroll
    for (int q = 0; q < 4; ++q) { h[q] = bf16h(ff[q]); l[q] = bf16h(ff[q] - bf16f(h[q])); }
    *reinterpret_cast<uint2*>(Hh + i) = make_uint2(h[0] | (h[1] << 16), h[2] | (h[3] << 16));
    *reinterpret_cast<uint2*>(Hl + i) = make_uint2(l[0] | (l[1] << 16), l[2] | (l[3] << 16));
}

__device__ __forceinline__ void d_tr(const float* __restrict__ W,
                                     ushort_t* __restrict__ Th,
                                     ushort_t* __restrict__ Tl,
                                     int K, int N, int bid) {
    __shared__ float t[32][33];
    int ntn = N >> 5;
    int kt = bid / ntn, nt = bid - kt * ntn;
    int k0 = kt * 32, n0 = nt * 32;
    int ty = threadIdx.x >> 3, tx = (threadIdx.x & 7) * 4;
    float4 f = ld4(W + (size_t)(k0 + ty) * N + n0 + tx);
    t[ty][tx] = f.x; t[ty][tx + 1] = f.y; t[ty][tx + 2] = f.z; t[ty][tx + 3] = f.w;
    __syncthreads();
    unsigned h[4], l[4];
    #pragma unroll
    for (int q = 0; q < 4; ++q) {
        float x = t[tx + q][ty];
        h[q] = bf16h(x); l[q] = bf16h(x - bf16f(h[q]));
    }
    size_t o = (size_t)(n0 + ty) * K + k0 + tx;
    *reinterpret_cast<uint2*>(Th + o) = make_uint2(h[0] | (h[1] << 16), h[2] | (h[3] << 16));
    *reinterpret_cast<uint2*>(Tl + o) = make_uint2(l[0] | (l[1] << 16), l[2] | (l[3] << 16));
}

__global__ __launch_bounds__(256) void prep(
    const float* __restrict__ h_s, const float* __restrict__ WQo,
    const float* __restrict__ WQi, const float* __restrict__ WKo,
    const float* __restrict__ WKi, const float* __restrict__ WVi,
    const float* __restrict__ W1, const float* __restrict__ W2,
    ushort_t* peh, ushort_t* pel, ushort_t* hsh, ushort_t* hsl,
    ushort_t* WQoth, ushort_t* WQotl, ushort_t* WQith, ushort_t* WQitl,
    ushort_t* WKoh, ushort_t* WKol, ushort_t* WKih, ushort_t* WKil,
    ushort_t* WVith, ushort_t* WVitl, ushort_t* W1th, ushort_t* W1tl,
    ushort_t* W2th, ushort_t* W2tl) {
    int bid = blockIdx.x;
    if (bid < 257) {
        // PE table: row p, pair index i -> sin/cos, as bf16 hi/lo ([257][512])
        int p = bid, i = threadIdx.x;
        const float c = -0.017988946039015984f; // -ln(10000)/512
        float div = expf((float)(2 * i) * c);
        float arg = (float)p * div;
        float s = sinf(arg), co = cosf(arg);
        unsigned hs = bf16h(s), hc = bf16h(co);
        unsigned ls = bf16h(s - bf16f(hs)), lc = bf16h(co - bf16f(hc));
        *reinterpret_cast<unsigned*>(peh + p * NA + 2 * i) = hs | (hc << 16);
        *reinterpret_cast<unsigned*>(pel + p * NA + 2 * i) = ls | (lc << 16);
        return;
    }
    if ((bid -= 257) < 512)  { d_ew(h_s, hsh, hsl, bid); return; }
    if ((bid -= 512) < 1024) { d_tr(WQo, WQoth, WQotl, DE, DM, bid); return; }
    if ((bid -= 1024) < 1024){ d_tr(WQi, WQith, WQitl, DE, DM, bid); return; }
    if ((bid -= 1024) < 512) { d_ew(WKo, WKoh, WKol, bid); return; }
    if ((bid -= 512) < 512)  { d_ew(WKi, WKih, WKil, bid); return; }
    if ((bid -= 512) < 512)  { d_tr(WVi, WVith, WVitl, NA, DM, bid); return; }
    if ((bid -= 512) < 2048) { d_tr(W1, W1th, W1tl, DE + DM, DM, bid); return; }
    bid -= 2048;               d_tr(W2, W2th, W2tl, DM, NA, bid);
}

// ================= split-bf16 MFMA GEMM (pre-split A and B) ===================
// C[M,N] = (Ah+Al)[M,K] @ (Bh+Bl)[N,K]^T, 3-product split accumulated in fp32.
// blockIdx.z selects between two parameter sets (batched pair launches).
// CONCAT: A rows are [A | A2] split at column KS (each half stride KS / K-KS).
template<int BIAS, int RELU, int GUARD, int CFOUT, int CHOUT, int CONCAT>
__global__ __launch_bounds__(256) void gemm2(
    const ushort_t* Ah0, const ushort_t* Al0,
    const ushort_t* Bh0, const ushort_t* Bl0,
    const float* bias0, float* Cf0, ushort_t* Ch0, ushort_t* Cl0, int N0,
    const ushort_t* Ah1, const ushort_t* Al1,
    const ushort_t* Bh1, const ushort_t* Bl1,
    const float* bias1, float* Cf1, ushort_t* Ch1, ushort_t* Cl1, int N1,
    const ushort_t* A2h, const ushort_t* A2l,
    int K, int KS) {
    const int z = blockIdx.z;
    const ushort_t* Ah = z ? Ah1 : Ah0;
    const ushort_t* Al = z ? Al1 : Al0;
    const ushort_t* Bh = z ? Bh1 : Bh0;
    const ushort_t* Bl = z ? Bl1 : Bl0;
    const float* bias  = z ? bias1 : bias0;
    float* Cf          = z ? Cf1 : Cf0;
    ushort_t* Chh      = z ? Ch1 : Ch0;
    ushort_t* Cll      = z ? Cl1 : Cl0;
    const int N        = z ? N1 : N0;

    const int row0 = blockIdx.y * 64, col0 = blockIdx.x * 64;
    if (GUARD && col0 >= N) return;

    __shared__ ushort_t sAh[4096], sAl[4096], sBh[4096], sBl[4096];
    const int tid = threadIdx.x;

    // staging: thread -> (row sr, 16-elem chunk at k16), XOR-swizzled in 8-groups
    const int sr  = tid >> 2;
    const int k16 = (tid & 3) * 16;
    const int swz = (sr & 7) << 3;
    const int si0 = sr * 64 + (k16 ^ swz);
    const int si1 = sr * 64 + ((k16 + 8) ^ swz);

    const int wid = tid >> 6, lane = tid & 63;
    const int wm = wid & 1, wn = wid >> 1;
    const int lm = lane & 15, lk = lane >> 4;

    const int ra = wm * 32 + lm;
    const int rb = wn * 32 + lm;
    const int aswz = (ra & 7) << 3;
    const int bswz = (rb & 7) << 3;

    const int nb = col0 + sr;
    const bool bval = !GUARD || (nb < N);
    const ushort_t* bhp = Bh + (size_t)nb * K;
    const ushort_t* blp = Bl + (size_t)nb * K;

    f4v acc[2][2] = {};

    for (int k0 = 0; k0 < K; k0 += 64) {
        // ---- stage A (pre-split hi/lo bf16) ----
        const ushort_t* aph; const ushort_t* apl; int ac, lda;
        if (CONCAT && k0 >= KS) { aph = A2h; apl = A2l; ac = k0 - KS; lda = K - KS; }
        else                    { aph = Ah;  apl = Al;  ac = k0;      lda = KS; }
        {
            size_t ao = (size_t)(row0 + sr) * lda + ac + k16;
            int4 a0 = *reinterpret_cast<const int4*>(aph + ao);
            int4 a1 = *reinterpret_cast<const int4*>(aph + ao + 8);
            int4 a2 = *reinterpret_cast<const int4*>(apl + ao);
            int4 a3 = *reinterpret_cast<const int4*>(apl + ao + 8);
            *reinterpret_cast<int4*>(&sAh[si0]) = a0;
            *reinterpret_cast<int4*>(&sAh[si1]) = a1;
            *reinterpret_cast<int4*>(&sAl[si0]) = a2;
            *reinterpret_cast<int4*>(&sAl[si1]) = a3;
        }
        // ---- stage B ----
        {
            int4 b0 = {0,0,0,0}, b1 = {0,0,0,0}, b2 = {0,0,0,0}, b3 = {0,0,0,0};
            if (bval) {
                b0 = *reinterpret_cast<const int4*>(bhp + k0 + k16);
                b1 = *reinterpret_cast<const int4*>(bhp + k0 + k16 + 8);
                b2 = *reinterpret_cast<const int4*>(blp + k0 + k16);
                b3 = *reinterpret_cast<const int4*>(blp + k0 + k16 + 8);
            }
            *reinterpret_cast<int4*>(&sBh[si0]) = b0;
            *reinterpret_cast<int4*>(&sBh[si1]) = b1;
            *reinterpret_cast<int4*>(&sBl[si0]) = b2;
            *reinterpret_cast<int4*>(&sBl[si1]) = b3;
        }
        __syncthreads();

        #pragma unroll
        for (int ks = 0; ks < 2; ++ks) {
            const int ka = (ks * 32 + lk * 8) ^ aswz;
            const int kb = (ks * 32 + lk * 8) ^ bswz;
            s8v a0h = *reinterpret_cast<const s8v*>(&sAh[ra * 64 + ka]);
            s8v a1h = *reinterpret_cast<const s8v*>(&sAh[(ra + 16) * 64 + ka]);
            s8v a0l = *reinterpret_cast<const s8v*>(&sAl[ra * 64 + ka]);
            s8v a1l = *reinterpret_cast<const s8v*>(&sAl[(ra + 16) * 64 + ka]);
            s8v b0h = *reinterpret_cast<const s8v*>(&sBh[rb * 64 + kb]);
            s8v b1h = *reinterpret_cast<const s8v*>(&sBh[(rb + 16) * 64 + kb]);
            s8v b0l = *reinterpret_cast<const s8v*>(&sBl[rb * 64 + kb]);
            s8v b1l = *reinterpret_cast<const s8v*>(&sBl[(rb + 16) * 64 + kb]);

            acc[0][0] = mfma16(a0h, b0h, acc[0][0]);
            acc[0][1] = mfma16(a0h, b1h, acc[0][1]);
            acc[1][0] = mfma16(a1h, b0h, acc[1][0]);
            acc[1][1] = mfma16(a1h, b1h, acc[1][1]);
            acc[0][0] = mfma16(a0h, b0l, acc[0][0]);
            acc[0][1] = mfma16(a0h, b1l, acc[0][1]);
            acc[1][0] = mfma16(a1h, b0l, acc[1][0]);
            acc[1][1] = mfma16(a1h, b1l, acc[1][1]);
            acc[0][0] = mfma16(a0l, b0h, acc[0][0]);
            acc[0][1] = mfma16(a0l, b1h, acc[0][1]);
            acc[1][0] = mfma16(a1l, b0h, acc[1][0]);
            acc[1][1] = mfma16(a1l, b1h, acc[1][1]);
        }
        __syncthreads();
    }

    // ---- epilogue: col=lane&15, row=(lane>>4)*4+reg ----
    #pragma unroll
    for (int i = 0; i < 2; ++i) {
        #pragma unroll
        for (int j = 0; j < 2; ++j) {
            int gc = col0 + wn * 32 + j * 16 + lm;
            if (GUARD && gc >= N) continue;
            float bv = BIAS ? bias[gc] : 0.0f;
            #pragma unroll
            for (int r = 0; r < 4; ++r) {
                int gr = row0 + wm * 32 + i * 16 + lk * 4 + r;
                float val = acc[i][j][r] + bv;
                if (RELU) val = fmaxf(val, 0.0f);
                size_t o = (size_t)gr * N + gc;
                if (CFOUT) Cf[o] = val;
                if (CHOUT) {
                    unsigned h = bf16h(val);
                    Chh[o] = (ushort_t)h;
                    Cll[o] = (ushort_t)bf16h(val - bf16f(h));
                }
            }
        }
    }
}

// ================= fused attention over phi (single pass over HBM) ============
// One block per b. Online softmax over 32-row chunks; chunk stashed in LDS so
// phi is read from HBM exactly once. Emits v (fp32) and w (bf16 hi/lo).
__global__ __launch_bounds__(256) void phi_attn(
    const float* __restrict__ phi, const float* __restrict__ uout,
    const float* __restrict__ uin, const float* __restrict__ po,
    const float* __restrict__ pi, float* __restrict__ v,
    ushort_t* __restrict__ wh, ushort_t* __restrict__ wl) {
    __shared__ float chunk[32 * 512];          // 64 KB
    __shared__ float sco[32], sci[32], eo[32], ei[32];
    __shared__ float sred[4];
    const int b = blockIdx.x, tid = threadIdx.x;
    const int wave = tid >> 6, lane = tid & 63;
    const float inv = 0.03125f; // 1/sqrt(1024)

    float4 uo0 = ld4(uout + (size_t)b * NA + lane * 4);
    float4 uo1 = ld4(uout + (size_t)b * NA + 256 + lane * 4);
    float4 ui0 = ld4(uin + (size_t)b * NA + lane * 4);
    float4 ui1 = ld4(uin + (size_t)b * NA + 256 + lane * 4);

    float mo = -3.0e38f, mi = -3.0e38f, Zo = 0.f, Zi = 0.f;
    float2 va = {0.f, 0.f}, Sa = {0.f, 0.f};

    for (int c = 0; c < NP; c += 32) {
        // phase A: score 32 rows (8 per wave), stash rows in LDS
        #pragma unroll
        for (int r = 0; r < 8; ++r) {
            int nl = wave * 8 + r;
            int n = c + nl;
            const float* row = phi + ((size_t)b * NP + n) * NA;
            float4 x0 = ld4(row + lane * 4);
            float4 x1 = ld4(row + 256 + lane * 4);
            *reinterpret_cast<float4*>(&chunk[nl * 512 + lane * 4]) = x0;
            *reinterpret_cast<float4*>(&chunk[nl * 512 + 256 + lane * 4]) = x1;
            float d0 = uo0.x * x0.x + uo0.y * x0.y + uo0.z * x0.z + uo0.w * x0.w
                     + uo1.x * x1.x + uo1.y * x1.y + uo1.z * x1.z + uo1.w * x1.w;
            float d1 = ui0.x * x0.x + ui0.y * x0.y + ui0.z * x0.z + ui0.w * x0.w
                     + ui1.x * x1.x + ui1.y * x1.y + ui1.z * x1.z + ui1.w * x1.w;
            for (int off = 32; off; off >>= 1) {
                d0 += __shfl_xor(d0, off);
                d1 += __shfl_xor(d1, off);
            }
            if (lane == 0) {
                sco[nl] = (d0 + po[b * NP + n]) * inv;
                sci[nl] = (d1 + pi[b * 257 + n + 1]) * inv;
            }
        }
        __syncthreads();
        // phase B: chunk maxes (wave0 -> out-head, wave1 -> in-head)
        if (wave == 0) {
            float x = sco[lane & 31];
            for (int off = 16; off; off >>= 1) x = fmaxf(x, __shfl_xor(x, off));
            if (lane == 0) sred[0] = x;
        } else if (wave == 1) {
            float x = sci[lane & 31];
            for (int off = 16; off; off >>= 1) x = fmaxf(x, __shfl_xor(x, off));
            if (lane == 0) sred[1] = x;
        }
        __syncthreads();
        float nmo = fmaxf(mo, sred[0]), nmi = fmaxf(mi, sred[1]);
        float fo = expf(mo - nmo), fi = expf(mi - nmi);
        va.x *= fo; va.y *= fo; Zo *= fo;
        Sa.x *= fi; Sa.y *= fi; Zi *= fi;
        if (tid < 32) eo[tid] = expf(sco[tid] - nmo);
        else if (tid >= 64 && tid < 96) ei[tid - 64] = expf(sci[tid - 64] - nmi);
        mo = nmo; mi = nmi;
        __syncthreads();
        // phase C: accumulate both weighted sums from LDS chunk
        #pragma unroll 4
        for (int n = 0; n < 32; ++n) {
            float e0 = eo[n], e1 = ei[n];
            float2 x = *reinterpret_cast<float2*>(&chunk[n * 512 + tid * 2]);
            va.x = fmaf(e0, x.x, va.x); va.y = fmaf(e0, x.y, va.y);
            Sa.x = fmaf(e1, x.x, Sa.x); Sa.y = fmaf(e1, x.y, Sa.y);
            Zo += e0; Zi += e1;
        }
        __syncthreads();
    }

    // finalize: v = va/Zo; in-head row-0 fixup -> w
    float iZo = 1.0f / Zo;
    float2 v2 = {va.x * iZo, va.y * iZo};
    *reinterpret_cast<float2*>(&v[(size_t)b * NA + tid * 2]) = v2;

    float2 ui2 = *reinterpret_cast<const float2*>(&uin[(size_t)b * NA + tid * 2]);
    float part = ui2.x * v2.x + ui2.y * v2.y;
    float dotv = blkred_sum(part, sred);
    float s0 = (dotv + pi[b * 257]) * inv;
    float e0 = expf(s0 - mi);
    float iZ = 1.0f / (Zi + e0);
    float wx = (e0 * v2.x + Sa.x) * iZ;
    float wy = (e0 * v2.y + Sa.y) * iZ;
    unsigned hx = bf16h(wx), hy = bf16h(wy);
    unsigned lx = bf16h(wx - bf16f(hx)), ly = bf16h(wy - bf16f(hy));
    *reinterpret_cast<unsigned*>(wh + (size_t)b * NA + tid * 2) = hx | (hy << 16);
    *reinterpret_cast<unsigned*>(wl + (size_t)b * NA + tid * 2) = lx | (ly << 16);
}

// ---------------- final: out = softmax(v + logits) ----------------------------
__global__ __launch_bounds__(256) void final_softmax(const float* __restrict__ v,
                                                     float* __restrict__ out) {
    __shared__ float smem[4];
    int b = blockIdx.x, t = threadIdx.x;
    float z0 = out[(size_t)b * NA + t] + v[(size_t)b * NA + t];
    float z1 = out[(size_t)b * NA + 256 + t] + v[(size_t)b * NA + 256 + t];
    float m = fmaxf(z0, z1);
    for (int off = 32; off; off >>= 1) m = fmaxf(m, __shfl_xor(m, off));
    int lane = t & 63, w = t >> 6;
    __syncthreads();
    if (lane == 0) smem[w] = m;
    __syncthreads();
    m = fmaxf(fmaxf(smem[0], smem[1]), fmaxf(smem[2], smem[3]));
    float e0 = expf(z0 - m), e1 = expf(z1 - m);
    float Z = blkred_sum(e0 + e1, smem);
    out[(size_t)b * NA + t] = e0 / Z;
    out[(size_t)b * NA + 256 + t] = e1 / Z;
}

// ---------------- launch ------------------------------------------------------
extern "C" void kernel_launch(void* const* d_in, const int* in_sizes, int n_in,
                              void* d_out, int out_size, void* d_ws, size_t ws_size,
                              hipStream_t stream) {
    const float* h_s = (const float*)d_in[0];
    const float* phi = (const float*)d_in[1];
    const float* WQo = (const float*)d_in[2];
    const float* WKo = (const float*)d_in[3];
    const float* WQi = (const float*)d_in[4];
    const float* WKi = (const float*)d_in[5];
    const float* WVi = (const float*)d_in[6];
    const float* W1  = (const float*)d_in[7];
    const float* b1  = (const float*)d_in[8];
    const float* W2  = (const float*)d_in[9];
    const float* b2  = (const float*)d_in[10];
    float* out = (float*)d_out;
    float* wsf = (float*)d_ws;

    size_t off = 0;
    auto af = [&](size_t n) { float* p = wsf + off; off += (n + 3) & ~(size_t)3; return p; };
    auto au = [&](size_t n) { ushort_t* p = (ushort_t*)(wsf + off); off += ((n / 2) + 3) & ~(size_t)3; return p; };

    // bf16 hi/lo weights ([N][K] for B-operand)
    ushort_t* peh   = au(257 * NA);      ushort_t* pel   = au(257 * NA);
    ushort_t* hsh   = au((size_t)BB*DE); ushort_t* hsl   = au((size_t)BB*DE);
    ushort_t* WQoth = au(DM * DE);       ushort_t* WQotl = au(DM * DE);
    ushort_t* WQith = au(DM * DE);       ushort_t* WQitl = au(DM * DE);
    ushort_t* WKoh  = au(NA * DM);       ushort_t* WKol  = au(NA * DM);
    ushort_t* WKih  = au(NA * DM);       ushort_t* WKil  = au(NA * DM);
    ushort_t* WVith = au(DM * NA);       ushort_t* WVitl = au(DM * NA);
    ushort_t* W1th  = au((size_t)DM * (DE+DM)); ushort_t* W1tl = au((size_t)DM * (DE+DM));
    ushort_t* W2th  = au(NA * DM);       ushort_t* W2tl  = au(NA * DM);

    // activations
    ushort_t* qoh = au((size_t)BB*DM);   ushort_t* qol = au((size_t)BB*DM);
    ushort_t* qih = au((size_t)BB*DM);   ushort_t* qil = au((size_t)BB*DM);
    float* uout = af((size_t)BB * NA);   float* uin = af((size_t)BB * NA);
    ushort_t* uoh = au((size_t)BB*NA);   ushort_t* uol = au((size_t)BB*NA);
    ushort_t* uih = au((size_t)BB*NA);   ushort_t* uil = au((size_t)BB*NA);
    float* po   = af((size_t)BB * NP);
    float* pi   = af((size_t)BB * 257);
    float* v    = af((size_t)BB * NA);
    ushort_t* wh  = au((size_t)BB*NA);   ushort_t* wl  = au((size_t)BB*NA);
    ushort_t* ctxh= au((size_t)BB*DM);   ushort_t* ctxl= au((size_t)BB*DM);
    ushort_t* hidh= au((size_t)BB*DM);   ushort_t* hidl= au((size_t)BB*DM);

    // 1. prep: PE + h_s split + all weight splits/transposes
    prep<<<6913, 256, 0, stream>>>(h_s, WQo, WQi, WKo, WKi, WVi, W1, W2,
                                   peh, pel, hsh, hsl,
                                   WQoth, WQotl, WQith, WQitl,
                                   WKoh, WKol, WKih, WKil,
                                   WVith, WVitl, W1th, W1tl, W2th, W2tl);

    // 2. qcat: q_out = h_s@WQo (z=0), q_in = h_s@WQi (z=1) -> hi/lo only
    gemm2<0,0,0,0,1,0><<<dim3(16, 8, 2), 256, 0, stream>>>(
        hsh, hsl, WQoth, WQotl, nullptr, nullptr, qoh, qol, DM,
        hsh, hsl, WQith, WQitl, nullptr, nullptr, qih, qil, DM,
        nullptr, nullptr, DE, DE);

    // 3. ucat: u_out = q_out@WKo^T (z=0), u_in = q_in@WKi^T (z=1) -> fp32 + hi/lo
    gemm2<0,0,0,1,1,0><<<dim3(8, 8, 2), 256, 0, stream>>>(
        qoh, qol, WKoh, WKol, nullptr, uout, uoh, uol, NA,
        qih, qil, WKih, WKil, nullptr, uin,  uih, uil, NA,
        nullptr, nullptr, DM, DM);

    // 4. pecat: po = u_out@pe[0:256]^T (z=0), pi = u_in@pe[0:257]^T (z=1)
    gemm2<0,0,1,1,0,0><<<dim3(5, 8, 2), 256, 0, stream>>>(
        uoh, uol, peh, pel, nullptr, po, nullptr, nullptr, NP,
        uih, uil, peh, pel, nullptr, pi, nullptr, nullptr, 257,
        nullptr, nullptr, NA, NA);

    // 5. fused attention over phi -> v (fp32), w (hi/lo)
    phi_attn<<<BB, 256, 0, stream>>>(phi, uout, uin, po, pi, v, wh, wl);

    // 6. ctx = w@WVi^T(pre-tr) -> hi/lo
    gemm2<0,0,0,0,1,0><<<dim3(16, 8, 1), 256, 0, stream>>>(
        wh, wl, WVith, WVitl, nullptr, nullptr, ctxh, ctxl, DM,
        wh, wl, WVith, WVitl, nullptr, nullptr, ctxh, ctxl, DM,
        nullptr, nullptr, NA, NA);

    // 7. hidden = relu([h_s|ctx]@W1 + b1) -> hi/lo   (CONCAT at KS=1024)
    gemm2<1,1,0,0,1,1><<<dim3(16, 8, 1), 256, 0, stream>>>(
        hsh, hsl, W1th, W1tl, b1, nullptr, hidh, hidl, DM,
        hsh, hsl, W1th, W1tl, b1, nullptr, hidh, hidl, DM,
        ctxh, ctxl, DE + DM, DE);

    // 8. logits = hidden@W2 + b2 -> out (fp32)
    gemm2<1,0,0,1,0,0><<<dim3(8, 8, 1), 256, 0, stream>>>(
        hidh, hidl, W2th, W2tl, b2, out, nullptr, nullptr, NA,
        hidh, hidl, W2th, W2tl, b2, out, nullptr, nullptr, NA,
        nullptr, nullptr, DM, DM);

    // 9. out = softmax(v + logits)
    final_softmax<<<BB, 256, 0, stream>>>(v, out);
}

// Round 4
// 189.818 us; speedup vs baseline: 3.9013x; 1.1576x over previous
//
#include <hip/hip_runtime.h>
#include <math.h>

// Problem dims
#define BB 512
#define DE 1024
#define DM 1024
#define NA 512
#define NP 256

typedef unsigned short ushort_t;
typedef __attribute__((ext_vector_type(8))) short s8v;   // 8 bf16 (4 VGPRs)
typedef __attribute__((ext_vector_type(4))) float f4v;   // 4 fp32 acc

static __device__ __forceinline__ float4 ld4(const float* p) {
    return *reinterpret_cast<const float4*>(p);
}

// RNE float -> bf16 bits
__device__ __forceinline__ unsigned bf16h(float x) {
    unsigned u = __float_as_uint(x);
    return (u + 0x7FFFu + ((u >> 16) & 1u)) >> 16;
}
__device__ __forceinline__ float bf16f(unsigned h) { return __uint_as_float(h << 16); }

__device__ __forceinline__ f4v mfma16(s8v a, s8v b, f4v c) {
    return __builtin_amdgcn_mfma_f32_16x16x32_bf16(a, b, c, 0, 0, 0);
}

// ================= PREP: PE table + all weight/h_s hi-lo splits ===============
__device__ __forceinline__ void d_ew(const float* __restrict__ W,
                                     ushort_t* __restrict__ Hh,
                                     ushort_t* __restrict__ Hl, int bid) {
    int i = (bid * 256 + threadIdx.x) * 4;
    float4 f = ld4(W + i);
    float ff[4] = {f.x, f.y, f.z, f.w};
    unsigned h[4], l[4];
    #pragma unroll
    for (int q = 0; q < 4; ++q) { h[q] = bf16h(ff[q]); l[q] = bf16h(ff[q] - bf16f(h[q])); }
    *reinterpret_cast<uint2*>(Hh + i) = make_uint2(h[0] | (h[1] << 16), h[2] | (h[3] << 16));
    *reinterpret_cast<uint2*>(Hl + i) = make_uint2(l[0] | (l[1] << 16), l[2] | (l[3] << 16));
}

__device__ __forceinline__ void d_tr(const float* __restrict__ W,
                                     ushort_t* __restrict__ Th,
                                     ushort_t* __restrict__ Tl,
                                     int K, int N, int bid) {
    __shared__ float t[32][33];
    int ntn = N >> 5;
    int kt = bid / ntn, nt = bid - kt * ntn;
    int k0 = kt * 32, n0 = nt * 32;
    int ty = threadIdx.x >> 3, tx = (threadIdx.x & 7) * 4;
    float4 f = ld4(W + (size_t)(k0 + ty) * N + n0 + tx);
    t[ty][tx] = f.x; t[ty][tx + 1] = f.y; t[ty][tx + 2] = f.z; t[ty][tx + 3] = f.w;
    __syncthreads();
    unsigned h[4], l[4];
    #pragma unroll
    for (int q = 0; q < 4; ++q) {
        float x = t[tx + q][ty];
        h[q] = bf16h(x); l[q] = bf16h(x - bf16f(h[q]));
    }
    size_t o = (size_t)(n0 + ty) * K + k0 + tx;
    *reinterpret_cast<uint2*>(Th + o) = make_uint2(h[0] | (h[1] << 16), h[2] | (h[3] << 16));
    *reinterpret_cast<uint2*>(Tl + o) = make_uint2(l[0] | (l[1] << 16), l[2] | (l[3] << 16));
}

__global__ __launch_bounds__(256) void prep(
    const float* __restrict__ h_s, const float* __restrict__ WQo,
    const float* __restrict__ WQi, const float* __restrict__ WKo,
    const float* __restrict__ WKi, const float* __restrict__ WVi,
    const float* __restrict__ W1, const float* __restrict__ W2,
    ushort_t* peh, ushort_t* pel, ushort_t* hsh, ushort_t* hsl,
    ushort_t* WQoh, ushort_t* WQol, ushort_t* WQih, ushort_t* WQil,
    ushort_t* WKoh, ushort_t* WKol, ushort_t* WKih, ushort_t* WKil,
    ushort_t* WVith, ushort_t* WVitl, ushort_t* W1th, ushort_t* W1tl,
    ushort_t* W2th, ushort_t* W2tl) {
    int bid = blockIdx.x;
    if (bid < 257) {
        // PE table: row p, pair index i -> sin/cos, as bf16 hi/lo ([257][512])
        int p = bid, i = threadIdx.x;
        const float c = -0.017988946039015984f; // -ln(10000)/512
        float div = expf((float)(2 * i) * c);
        float arg = (float)p * div;
        float s = sinf(arg), co = cosf(arg);
        unsigned hs = bf16h(s), hc = bf16h(co);
        unsigned ls = bf16h(s - bf16f(hs)), lc = bf16h(co - bf16f(hc));
        *reinterpret_cast<unsigned*>(peh + p * NA + 2 * i) = hs | (hc << 16);
        *reinterpret_cast<unsigned*>(pel + p * NA + 2 * i) = ls | (lc << 16);
        return;
    }
    if ((bid -= 257) < 512)  { d_ew(h_s, hsh, hsl, bid); return; }
    if ((bid -= 512) < 1024) { d_ew(WQo, WQoh, WQol, bid); return; }
    if ((bid -= 1024) < 1024){ d_ew(WQi, WQih, WQil, bid); return; }
    if ((bid -= 1024) < 512) { d_ew(WKo, WKoh, WKol, bid); return; }
    if ((bid -= 512) < 512)  { d_ew(WKi, WKih, WKil, bid); return; }
    if ((bid -= 512) < 512)  { d_tr(WVi, WVith, WVitl, NA, DM, bid); return; }
    if ((bid -= 512) < 2048) { d_tr(W1, W1th, W1tl, DE + DM, DM, bid); return; }
    bid -= 2048;               d_tr(W2, W2th, W2tl, DM, NA, bid);
}

// ================= split-bf16 MFMA GEMM, 32x64 tile ===========================
// C[M,N] = (Ah+Al)[M,K](lda) @ (Bh+Bl)[N,K]^T, 3-product split, fp32 accum.
// 4 waves: wm=wid&1 (16-row half), wn=wid>>1 (32-col half); acc[2] frags.
// blockIdx.z selects between two parameter sets.
// CONCAT: A columns >= KS come from A2 (same lda).
template<int BIAS, int RELU, int GUARD, int CFOUT, int CHOUT, int CONCAT>
__global__ __launch_bounds__(256) void gemm32(
    const ushort_t* Ah0, const ushort_t* Al0,
    const ushort_t* Bh0, const ushort_t* Bl0,
    const float* bias0, float* Cf0, ushort_t* Ch0, ushort_t* Cl0,
    int N0, int ldc0,
    const ushort_t* Ah1, const ushort_t* Al1,
    const ushort_t* Bh1, const ushort_t* Bl1,
    const float* bias1, float* Cf1, ushort_t* Ch1, ushort_t* Cl1,
    int N1, int ldc1,
    const ushort_t* A2h, const ushort_t* A2l,
    int lda, int K, int KS) {
    const int z = blockIdx.z;
    const ushort_t* Ah = z ? Ah1 : Ah0;
    const ushort_t* Al = z ? Al1 : Al0;
    const ushort_t* Bh = z ? Bh1 : Bh0;
    const ushort_t* Bl = z ? Bl1 : Bl0;
    const float* bias  = z ? bias1 : bias0;
    float* Cf          = z ? Cf1 : Cf0;
    ushort_t* Chh      = z ? Ch1 : Ch0;
    ushort_t* Cll      = z ? Cl1 : Cl0;
    const int N        = z ? N1 : N0;
    const int ldc      = z ? ldc1 : ldc0;

    const int row0 = blockIdx.y * 32, col0 = blockIdx.x * 64;
    if (GUARD && col0 >= N) return;

    __shared__ ushort_t sAh[2048], sAl[2048], sBh[4096], sBl[4096];
    const int tid = threadIdx.x;

    // A staging: 32 rows x 8-elem chunk per thread
    const int ar = tid >> 3;            // 0..31
    const int ak = (tid & 7) * 8;       // 0..56
    const int asi = ar * 64 + (ak ^ ((ar & 7) << 3));
    // B staging: 64 rows x 16-elem chunk per thread
    const int br = tid >> 2;            // 0..63
    const int bk = (tid & 3) * 16;
    const int bsw = (br & 7) << 3;
    const int bsi0 = br * 64 + (bk ^ bsw);
    const int bsi1 = br * 64 + ((bk + 8) ^ bsw);

    const int wid = tid >> 6, lane = tid & 63;
    const int wm = wid & 1, wn = wid >> 1;
    const int lm = lane & 15, lk = lane >> 4;
    const int ra = wm * 16 + lm;
    const int rb = wn * 32 + lm;        // +16 for j=1
    const int aswz = (ra & 7) << 3;
    const int bswz = (rb & 7) << 3;

    const int nb = col0 + br;
    const bool bval = !GUARD || (nb < N);
    const ushort_t* bhp = Bh + (size_t)nb * K;
    const ushort_t* blp = Bl + (size_t)nb * K;

    f4v acc[2] = {};

    for (int k0 = 0; k0 < K; k0 += 64) {
        // ---- stage A ----
        const ushort_t* aph; const ushort_t* apl; int ac;
        if (CONCAT && k0 >= KS) { aph = A2h; apl = A2l; ac = k0 - KS; }
        else                    { aph = Ah;  apl = Al;  ac = k0; }
        {
            size_t ao = (size_t)(row0 + ar) * lda + ac + ak;
            int4 a0 = *reinterpret_cast<const int4*>(aph + ao);
            int4 a1 = *reinterpret_cast<const int4*>(apl + ao);
            *reinterpret_cast<int4*>(&sAh[asi]) = a0;
            *reinterpret_cast<int4*>(&sAl[asi]) = a1;
        }
        // ---- stage B ----
        {
            int4 b0 = {0,0,0,0}, b1 = {0,0,0,0}, b2 = {0,0,0,0}, b3 = {0,0,0,0};
            if (bval) {
                b0 = *reinterpret_cast<const int4*>(bhp + k0 + bk);
                b1 = *reinterpret_cast<const int4*>(bhp + k0 + bk + 8);
                b2 = *reinterpret_cast<const int4*>(blp + k0 + bk);
                b3 = *reinterpret_cast<const int4*>(blp + k0 + bk + 8);
            }
            *reinterpret_cast<int4*>(&sBh[bsi0]) = b0;
            *reinterpret_cast<int4*>(&sBh[bsi1]) = b1;
            *reinterpret_cast<int4*>(&sBl[bsi0]) = b2;
            *reinterpret_cast<int4*>(&sBl[bsi1]) = b3;
        }
        __syncthreads();

        #pragma unroll
        for (int ks = 0; ks < 2; ++ks) {
            const int ka = (ks * 32 + lk * 8) ^ aswz;
            const int kb = (ks * 32 + lk * 8) ^ bswz;
            s8v a_h = *reinterpret_cast<const s8v*>(&sAh[ra * 64 + ka]);
            s8v a_l = *reinterpret_cast<const s8v*>(&sAl[ra * 64 + ka]);
            s8v b0h = *reinterpret_cast<const s8v*>(&sBh[rb * 64 + kb]);
            s8v b1h = *reinterpret_cast<const s8v*>(&sBh[(rb + 16) * 64 + kb]);
            s8v b0l = *reinterpret_cast<const s8v*>(&sBl[rb * 64 + kb]);
            s8v b1l = *reinterpret_cast<const s8v*>(&sBl[(rb + 16) * 64 + kb]);

            acc[0] = mfma16(a_h, b0h, acc[0]);
            acc[1] = mfma16(a_h, b1h, acc[1]);
            acc[0] = mfma16(a_h, b0l, acc[0]);
            acc[1] = mfma16(a_h, b1l, acc[1]);
            acc[0] = mfma16(a_l, b0h, acc[0]);
            acc[1] = mfma16(a_l, b1h, acc[1]);
        }
        __syncthreads();
    }

    // ---- epilogue: col=lane&15, row=(lane>>4)*4+reg ----
    #pragma unroll
    for (int j = 0; j < 2; ++j) {
        int gc = col0 + wn * 32 + j * 16 + lm;
        if (GUARD && gc >= N) continue;
        float bv = BIAS ? bias[gc] : 0.0f;
        #pragma unroll
        for (int r = 0; r < 4; ++r) {
            int gr = row0 + wm * 16 + lk * 4 + r;
            float val = acc[j][r] + bv;
            if (RELU) val = fmaxf(val, 0.0f);
            size_t o = (size_t)gr * ldc + gc;
            if (CFOUT) Cf[o] = val;
            if (CHOUT) {
                unsigned h = bf16h(val);
                Chh[o] = (ushort_t)h;
                Cll[o] = (ushort_t)bf16h(val - bf16f(h));
            }
        }
    }
}

// ================= fused attention over phi (single HBM pass) =================
// 512 threads/block, one block per b. 16-row chunks staged in REGISTERS:
// score from regs -> ds_write chunk -> prefetch next chunk (stays in flight
// across both barriers) -> redundant online-softmax update -> accumulate.
__global__ __launch_bounds__(512) void phi_attn(
    const float* __restrict__ phi, const float* __restrict__ Ubig,
    const float* __restrict__ po, const float* __restrict__ pi,
    float* __restrict__ v, ushort_t* __restrict__ wh, ushort_t* __restrict__ wl) {
    __shared__ float chunk[16 * 512];   // 32 KB
    __shared__ float sco[2][16], sci[2][16];
    __shared__ float sred[8];
    const int b = blockIdx.x, tid = threadIdx.x;
    const int wave = tid >> 6, lane = tid & 63;
    const float inv = 0.03125f; // 1/sqrt(1024)

    const float* uo = Ubig + (size_t)b * 1024;
    const float* ui = uo + 512;
    float4 uo0 = ld4(uo + lane * 8), uo1 = ld4(uo + lane * 8 + 4);
    float4 ui0 = ld4(ui + lane * 8), ui1 = ld4(ui + lane * 8 + 4);
    const float* pb = phi + (size_t)b * NP * NA;

    // preload chunk 0: this wave's rows {wave*2, wave*2+1}
    float4 x00, x01, x10, x11;
    {
        const float* r0 = pb + (size_t)(wave * 2) * NA + lane * 8;
        x00 = ld4(r0); x01 = ld4(r0 + 4);
        x10 = ld4(r0 + NA); x11 = ld4(r0 + NA + 4);
    }

    float mo = -3.0e38f, mi = -3.0e38f;
    float Zo = 0.f, Zi = 0.f, va = 0.f, Sa = 0.f;

    for (int c = 0; c < 16; ++c) {
        const int p = c & 1;
        // ---- score 2 rows from regs ----
        {
            float d0a = uo0.x*x00.x + uo0.y*x00.y + uo0.z*x00.z + uo0.w*x00.w
                      + uo1.x*x01.x + uo1.y*x01.y + uo1.z*x01.z + uo1.w*x01.w;
            float d1a = ui0.x*x00.x + ui0.y*x00.y + ui0.z*x00.z + ui0.w*x00.w
                      + ui1.x*x01.x + ui1.y*x01.y + ui1.z*x01.z + ui1.w*x01.w;
            float d0b = uo0.x*x10.x + uo0.y*x10.y + uo0.z*x10.z + uo0.w*x10.w
                      + uo1.x*x11.x + uo1.y*x11.y + uo1.z*x11.z + uo1.w*x11.w;
            float d1b = ui0.x*x10.x + ui0.y*x10.y + ui0.z*x10.z + ui0.w*x10.w
                      + ui1.x*x11.x + ui1.y*x11.y + ui1.z*x11.z + ui1.w*x11.w;
            for (int off = 32; off; off >>= 1) {
                d0a += __shfl_xor(d0a, off); d1a += __shfl_xor(d1a, off);
                d0b += __shfl_xor(d0b, off); d1b += __shfl_xor(d1b, off);
            }
            if (lane == 0) {
                int n0 = c * 16 + wave * 2;
                sco[p][wave*2]     = (d0a + po[b * NP + n0]) * inv;
                sci[p][wave*2]     = (d1a + pi[b * 257 + n0 + 1]) * inv;
                sco[p][wave*2 + 1] = (d0b + po[b * NP + n0 + 1]) * inv;
                sci[p][wave*2 + 1] = (d1b + pi[b * 257 + n0 + 2]) * inv;
            }
        }
        __syncthreads();   // prev accumulate done; safe to overwrite chunk
        // ---- ds_write chunk ----
        {
            float* c0 = &chunk[(wave * 2) * 512 + lane * 8];
            *reinterpret_cast<float4*>(c0) = x00;
            *reinterpret_cast<float4*>(c0 + 4) = x01;
            *reinterpret_cast<float4*>(c0 + 512) = x10;
            *reinterpret_cast<float4*>(c0 + 516) = x11;
        }
        // ---- prefetch next chunk into regs (in flight across barrier) ----
        if (c + 1 < 16) {
            const float* r0 = pb + (size_t)((c + 1) * 16 + wave * 2) * NA + lane * 8;
            x00 = ld4(r0); x01 = ld4(r0 + 4);
            x10 = ld4(r0 + NA); x11 = ld4(r0 + NA + 4);
        }
        __syncthreads();   // chunk + scores visible
        // ---- online-softmax update (redundant per-thread, deterministic) ----
        float nmo = mo, nmi = mi;
        #pragma unroll
        for (int n = 0; n < 16; ++n) {
            nmo = fmaxf(nmo, sco[p][n]);
            nmi = fmaxf(nmi, sci[p][n]);
        }
        float fo = expf(mo - nmo), fi = expf(mi - nmi);
        va *= fo; Zo *= fo; Sa *= fi; Zi *= fi;
        mo = nmo; mi = nmi;
        // ---- accumulate own column ----
        #pragma unroll
        for (int n = 0; n < 16; ++n) {
            float e0 = expf(sco[p][n] - mo);
            float e1 = expf(sci[p][n] - mi);
            float x = chunk[n * 512 + tid];
            va = fmaf(e0, x, va); Sa = fmaf(e1, x, Sa);
            Zo += e0; Zi += e1;
        }
    }

    // ---- finalize: v, then in-head row-0 fixup -> w ----
    float vv = va / Zo;
    v[(size_t)b * NA + tid] = vv;

    float part = ui[tid] * vv;
    for (int off = 32; off; off >>= 1) part += __shfl_xor(part, off);
    if (lane == 0) sred[wave] = part;
    __syncthreads();
    float dot = ((sred[0] + sred[1]) + (sred[2] + sred[3]))
              + ((sred[4] + sred[5]) + (sred[6] + sred[7]));
    float s0 = (dot + pi[b * 257]) * inv;
    float e0 = expf(s0 - mi);
    float iZ = 1.0f / (Zi + e0);
    float wv = (e0 * vv + Sa) * iZ;
    unsigned h = bf16h(wv);
    wh[(size_t)b * NA + tid] = (ushort_t)h;
    wl[(size_t)b * NA + tid] = (ushort_t)bf16h(wv - bf16f(h));
}

// ---------------- final: out = softmax(v + logits) ----------------------------
__global__ __launch_bounds__(256) void final_softmax(const float* __restrict__ v,
                                                     float* __restrict__ out) {
    __shared__ float smem[4];
    int b = blockIdx.x, t = threadIdx.x;
    int lane = t & 63, w = t >> 6;
    float z0 = out[(size_t)b * NA + t] + v[(size_t)b * NA + t];
    float z1 = out[(size_t)b * NA + 256 + t] + v[(size_t)b * NA + 256 + t];
    float m = fmaxf(z0, z1);
    for (int off = 32; off; off >>= 1) m = fmaxf(m, __shfl_xor(m, off));
    __syncthreads();
    if (lane == 0) smem[w] = m;
    __syncthreads();
    m = fmaxf(fmaxf(smem[0], smem[1]), fmaxf(smem[2], smem[3]));
    float e0 = expf(z0 - m), e1 = expf(z1 - m);
    float s = e0 + e1;
    for (int off = 32; off; off >>= 1) s += __shfl_xor(s, off);
    __syncthreads();
    if (lane == 0) smem[w] = s;
    __syncthreads();
    float Z = (smem[0] + smem[1]) + (smem[2] + smem[3]);
    out[(size_t)b * NA + t] = e0 / Z;
    out[(size_t)b * NA + 256 + t] = e1 / Z;
}

// ---------------- launch ------------------------------------------------------
extern "C" void kernel_launch(void* const* d_in, const int* in_sizes, int n_in,
                              void* d_out, int out_size, void* d_ws, size_t ws_size,
                              hipStream_t stream) {
    const float* h_s = (const float*)d_in[0];
    const float* phi = (const float*)d_in[1];
    const float* WQo = (const float*)d_in[2];
    const float* WKo = (const float*)d_in[3];
    const float* WQi = (const float*)d_in[4];
    const float* WKi = (const float*)d_in[5];
    const float* WVi = (const float*)d_in[6];
    const float* W1  = (const float*)d_in[7];
    const float* b1  = (const float*)d_in[8];
    const float* W2  = (const float*)d_in[9];
    const float* b2  = (const float*)d_in[10];
    float* out = (float*)d_out;
    float* wsf = (float*)d_ws;

    size_t off = 0;
    auto af = [&](size_t n) { float* p = wsf + off; off += (n + 3) & ~(size_t)3; return p; };
    auto au = [&](size_t n) { ushort_t* p = (ushort_t*)(wsf + off); off += ((n / 2) + 3) & ~(size_t)3; return p; };

    // bf16 hi/lo buffers
    ushort_t* peh   = au(257 * NA);          ushort_t* pel   = au(257 * NA);
    ushort_t* hsh   = au((size_t)BB*DE);     ushort_t* hsl   = au((size_t)BB*DE);
    ushort_t* WQoh  = au((size_t)DE*DM);     ushort_t* WQol  = au((size_t)DE*DM);
    ushort_t* WQih  = au((size_t)DE*DM);     ushort_t* WQil  = au((size_t)DE*DM);
    ushort_t* WKoh  = au((size_t)NA*DM);     ushort_t* WKol  = au((size_t)NA*DM);
    ushort_t* WKih  = au((size_t)NA*DM);     ushort_t* WKil  = au((size_t)NA*DM);
    ushort_t* WVith = au((size_t)DM*NA);     ushort_t* WVitl = au((size_t)DM*NA);
    ushort_t* W1th  = au((size_t)DM*(DE+DM));ushort_t* W1tl  = au((size_t)DM*(DE+DM));
    ushort_t* W2th  = au((size_t)NA*DM);     ushort_t* W2tl  = au((size_t)NA*DM);
    // combined score weights: rows 0-511 = out-head, 512-1023 = in-head, K=DE
    ushort_t* Wbigh = au((size_t)1024*DE);   ushort_t* Wbigl = au((size_t)1024*DE);
    // activations
    float*    Ubig  = af((size_t)BB * 1024);
    ushort_t* Ubigh = au((size_t)BB*1024);   ushort_t* Ubigl = au((size_t)BB*1024);
    float*    po    = af((size_t)BB * NP);
    float*    pi    = af((size_t)BB * 257);
    float*    v     = af((size_t)BB * NA);
    ushort_t* wh    = au((size_t)BB*NA);     ushort_t* wl    = au((size_t)BB*NA);
    ushort_t* ctxh  = au((size_t)BB*DM);     ushort_t* ctxl  = au((size_t)BB*DM);
    ushort_t* hidh  = au((size_t)BB*DM);     ushort_t* hidl  = au((size_t)BB*DM);

    // 1. prep: PE + ew/tr splits
    prep<<<6913, 256, 0, stream>>>(h_s, WQo, WQi, WKo, WKi, WVi, W1, W2,
                                   peh, pel, hsh, hsl,
                                   WQoh, WQol, WQih, WQil,
                                   WKoh, WKol, WKih, WKil,
                                   WVith, WVitl, W1th, W1tl, W2th, W2tl);

    // 2. Wc^T[n,e] = sum_d WK[n,d]*WQ[e,d], both heads -> Wbig rows 0-511 / 512-1023
    gemm32<0,0,0,0,1,0><<<dim3(16, 16, 2), 256, 0, stream>>>(
        WKoh, WKol, WQoh, WQol, nullptr, nullptr, Wbigh, Wbigl, DE, DE,
        WKih, WKil, WQih, WQil, nullptr, nullptr, Wbigh + (size_t)512*DE, Wbigl + (size_t)512*DE, DE, DE,
        nullptr, nullptr, DM, DM, DM);

    // 3. U = h_s @ Wbig^T  (cols 0-511 = u_out, 512-1023 = u_in), fp32 + hi/lo
    gemm32<0,0,0,1,1,0><<<dim3(16, 16, 1), 256, 0, stream>>>(
        hsh, hsl, Wbigh, Wbigl, nullptr, Ubig, Ubigh, Ubigl, 1024, 1024,
        hsh, hsl, Wbigh, Wbigl, nullptr, Ubig, Ubigh, Ubigl, 1024, 1024,
        nullptr, nullptr, DE, DE, DE);

    // 4. pe dots: po = u_out@pe[0:256]^T (z=0), pi = u_in@pe[0:257]^T (z=1)
    gemm32<0,0,1,1,0,0><<<dim3(5, 16, 2), 256, 0, stream>>>(
        Ubigh, Ubigl, peh, pel, nullptr, po, nullptr, nullptr, NP, NP,
        Ubigh + 512, Ubigl + 512, peh, pel, nullptr, pi, nullptr, nullptr, 257, 257,
        nullptr, nullptr, 1024, NA, NA);

    // 5. fused attention over phi -> v (fp32), w (hi/lo)
    phi_attn<<<BB, 512, 0, stream>>>(phi, Ubig, po, pi, v, wh, wl);

    // 6. ctx = w @ WVi (pre-transposed) -> hi/lo
    gemm32<0,0,0,0,1,0><<<dim3(16, 16, 1), 256, 0, stream>>>(
        wh, wl, WVith, WVitl, nullptr, nullptr, ctxh, ctxl, DM, DM,
        wh, wl, WVith, WVitl, nullptr, nullptr, ctxh, ctxl, DM, DM,
        nullptr, nullptr, NA, NA, NA);

    // 7. hidden = relu([h_s|ctx] @ W1 + b1) -> hi/lo  (CONCAT at KS=1024)
    gemm32<1,1,0,0,1,1><<<dim3(16, 16, 1), 256, 0, stream>>>(
        hsh, hsl, W1th, W1tl, b1, nullptr, hidh, hidl, DM, DM,
        hsh, hsl, W1th, W1tl, b1, nullptr, hidh, hidl, DM, DM,
        ctxh, ctxl, DE, DE + DM, DE);

    // 8. logits = hidden @ W2 + b2 -> out (fp32)
    gemm32<1,0,0,1,0,0><<<dim3(8, 16, 1), 256, 0, stream>>>(
        hidh, hidl, W2th, W2tl, b2, out, nullptr, nullptr, NA, NA,
        hidh, hidl, W2th, W2tl, b2, out, nullptr, nullptr, NA, NA,
        nullptr, nullptr, DM, DM, DM);

    // 9. out = softmax(v + logits)
    final_softmax<<<BB, 256, 0, stream>>>(v, out);
}